// Round 8
// baseline (177.065 us; speedup 1.0000x reference)
//
#include <hip/hip_runtime.h>

#define NPTS 8192
#define KSEL 33     // rank 0 (self) + 32 neighbors
#define QB   8      // queries per block
#define NBLK (NPTS / QB)   // 1024 blocks -> exactly 4 blocks/CU, all resident
#define CAPQ 512    // survivor capacity per query. NOT 128: the per-wave
                    // 33rd-of-sample threshold lands at global rank ~100-150
                    // (1/4 sample => 33rd ~ 132nd globally). Round-7 failure
                    // was CAPQ=128 silently dropping survivors.

typedef float vf4 __attribute__((ext_vector_type(4)));

// ---------------------------------------------------------------------------
// Prep: pts4[j] = (x, y, z, sq), sq = (x*x + y*y) + z*z in exact reference
// rounding order (contract off, separate mul/add).
// ---------------------------------------------------------------------------
__global__ __launch_bounds__(256) void prep_kernel(const float* __restrict__ pts,
                                                   float4* __restrict__ pts4) {
#pragma clang fp contract(off)
    const int j = blockIdx.x * 256 + threadIdx.x;
    const float x = pts[j * 3 + 0];
    const float y = pts[j * 3 + 1];
    const float z = pts[j * 3 + 2];
    const float sq = (x * x + y * y) + z * z;
    pts4[j] = make_float4(x, y, z, sq);
}

// ---------------------------------------------------------------------------
// Fused exact-kNN + gather, 8 queries per block (amortized table scan).
// Thread owns j = tid + t*256 (same ownership as the verified round-6 kernel
// -> bit-identical per-thread dists, thresholds, survivors, ranks).
//
// pass 1: load pj once, update 8 queries' 2-smallest-d2 trackers.
// per-wave ballot binary search per query: 33rd smallest of the 128-value
//   {m1,m2} multiset = safe upper bound on true 33rd d2. min over waves.
// widen to sqrt-closure T2 (monotone CR sqrt; non-survivors strictly above
//   the 33rd dist even under tie-break). Bit-identical selection.
// pass 2: recompute d2 (identical IEEE op sequence), push survivors to
//   per-query LDS lists via atomics, CR sqrtf only for survivors.
// rank: all-pairs on u64 key (dist<<32|j) per query = lax.top_k order.
// gather: 8*57 = 456 rows x 1KB, wave-uniform row loop, 2-stage pipeline,
//   NT float4 stores.
// ---------------------------------------------------------------------------
__global__ __launch_bounds__(256) void knn_fused_kernel(const float4* __restrict__ pts4,
                                                        const float* __restrict__ feats,
                                                        float* __restrict__ out) {
#pragma clang fp contract(off)
    const int i0 = blockIdx.x * QB;
    const int tid = threadIdx.x;
    const int lane = tid & 63;
    const int wv = tid >> 6;

    __shared__ unsigned red[4][QB];
    __shared__ int cnt[QB];
    __shared__ unsigned long long S[QB][CAPQ];
    __shared__ unsigned jlist[QB][32];

    float4 pi[QB];
#pragma unroll
    for (int q = 0; q < QB; ++q) pi[q] = pts4[i0 + q];
    if (tid < QB) cnt[tid] = 0;

    // --- pass 1: shared pj loads, 8x 2-min trackers ---
    unsigned m1[QB], m2[QB];
#pragma unroll
    for (int q = 0; q < QB; ++q) { m1[q] = 0xFFFFFFFFu; m2[q] = 0xFFFFFFFFu; }

    for (int t = 0; t < 32; ++t) {
        const int j = tid + t * 256;
        const float4 pj = pts4[j];
#pragma unroll
        for (int q = 0; q < QB; ++q) {
            const float dot = __builtin_fmaf(pi[q].z, pj.z,
                               __builtin_fmaf(pi[q].y, pj.y, pi[q].x * pj.x));
            const float d2 = (pi[q].w + pj.w) - (2.0f * dot);
            const unsigned db = __float_as_uint(fmaxf(d2, 0.0f));
            const unsigned mx = db > m1[q] ? db : m1[q];
            m1[q] = db < m1[q] ? db : m1[q];
            m2[q] = mx < m2[q] ? mx : m2[q];
        }
    }

    // --- per-wave ballot binary search per query ---
#pragma unroll
    for (int q = 0; q < QB; ++q) {
        unsigned blo = 0u, bhi = 0x7F800000u;
        while (blo < bhi) {
            const unsigned mid = (blo + bhi) >> 1;
            const int c = __popcll(__ballot(m1[q] <= mid)) +
                          __popcll(__ballot(m2[q] <= mid));
            if (c >= KSEL) bhi = mid; else blo = mid + 1u;
        }
        if (lane == 0) red[wv][q] = bhi;
    }
    __syncthreads();

    unsigned T2[QB];
#pragma unroll
    for (int q = 0; q < QB; ++q) {
        unsigned T = red[0][q];
        T = red[1][q] < T ? red[1][q] : T;
        T = red[2][q] < T ? red[2][q] : T;
        T = red[3][q] < T ? red[3][q] : T;
        const float s = sqrtf(__uint_as_float(T));              // CR sqrt
        const float snx = __uint_as_float(__float_as_uint(s) + 1u);
        T2[q] = __float_as_uint(__fmul_rn(snx, snx)) + 2u;
    }

    // --- pass 2: recompute d2 (identical op sequence), push survivors ---
    for (int t = 0; t < 32; ++t) {
        const int j = tid + t * 256;
        const float4 pj = pts4[j];
#pragma unroll
        for (int q = 0; q < QB; ++q) {
            const float dot = __builtin_fmaf(pi[q].z, pj.z,
                               __builtin_fmaf(pi[q].y, pj.y, pi[q].x * pj.x));
            const float d2 = (pi[q].w + pj.w) - (2.0f * dot);
            const unsigned db = __float_as_uint(fmaxf(d2, 0.0f));
            if (db <= T2[q]) {
                const unsigned sb = __float_as_uint(sqrtf(__uint_as_float(db)));
                const int pos = atomicAdd(&cnt[q], 1);
                if (pos < CAPQ)
                    S[q][pos] = (((unsigned long long)sb) << 32) | (unsigned)j;
            }
        }
    }
    __syncthreads();

    // --- exact rank among survivors; wave-uniform q -> broadcast reads ---
    for (int q = 0; q < QB; ++q) {
        const int cq = cnt[q] < CAPQ ? cnt[q] : CAPQ;
        for (int u = tid; u < cq; u += 256) {
            const unsigned long long key = S[q][u];
            int rank = 0;
            for (int v = 0; v < cq; ++v) rank += (S[q][v] < key) ? 1 : 0;
            if (rank >= 1 && rank < KSEL) jlist[q][rank - 1] = (unsigned)key;
        }
    }
    __syncthreads();

    // --- gather: 456 rows (8 queries x 57), wave-uniform, 2-stage pipeline ---
    const unsigned long long O1 = (unsigned long long)NPTS * 256ull;
    const unsigned long long O2 = O1 + (unsigned long long)NPTS * 2048ull;
    const unsigned long long O3 = O2 + (unsigned long long)NPTS * 4096ull;

    auto row_addr = [&](int r, const float4** sp, float** dp) {
        const int q = r / 57;
        const int rr = r - q * 57;
        const unsigned long long i = (unsigned long long)(i0 + q);
        unsigned src;
        unsigned long long dst;
        if (rr == 0) {
            src = (unsigned)i;
            dst = i * 256ull;
        } else if (rr < 9) {
            const int k = rr - 1;
            src = jlist[q][k];
            dst = O1 + i * 2048ull + (unsigned long long)k * 256ull;
        } else if (rr < 25) {
            const int k = rr - 9;
            src = jlist[q][k];
            dst = O2 + i * 4096ull + (unsigned long long)k * 256ull;
        } else {
            const int k = rr - 25;
            src = jlist[q][k];
            dst = O3 + i * 8192ull + (unsigned long long)k * 256ull;
        }
        *sp = (const float4*)(feats + (unsigned long long)src * 256ull);
        *dp = (float*)(out + dst);
    };

    int r = wv;
    const float4* sp;
    float* dp;
    row_addr(r, &sp, &dp);
    vf4 v = ((const vf4*)sp)[lane];
    for (; r + 4 < QB * 57; r += 4) {
        const float4* spn;
        float* dpn;
        row_addr(r + 4, &spn, &dpn);
        const vf4 vn = ((const vf4*)spn)[lane];     // issue next load first
        __builtin_nontemporal_store(v, &((vf4*)dp)[lane]);
        v = vn;
        dp = dpn;
    }
    __builtin_nontemporal_store(v, &((vf4*)dp)[lane]);
}

extern "C" void kernel_launch(void* const* d_in, const int* in_sizes, int n_in,
                              void* d_out, int out_size, void* d_ws, size_t ws_size,
                              hipStream_t stream) {
    const float* feats = (const float*)d_in[0];   // (8192, 256) f32
    const float* pts = (const float*)d_in[1];     // (8192, 3)   f32
    // d_in[2] = f_masks (all ones; unused by the reference computation)

    float4* pts4 = (float4*)d_ws;                 // 128 KB scratch

    prep_kernel<<<NPTS / 256, 256, 0, stream>>>(pts, pts4);
    knn_fused_kernel<<<NBLK, 256, 0, stream>>>(pts4, feats, (float*)d_out);
}

// Round 9
// 155.367 us; speedup vs baseline: 1.1397x; 1.1397x over previous
//
#include <hip/hip_runtime.h>

#define NPTS 8192
#define KSEL 33    // rank 0 (self) + 32 neighbors
#define SCAP 512   // survivor capacity (per-wave 33rd-of-2048-sample threshold
                   // lands at global rank ~100-150; 128 was too small (round 7))

typedef float vf4 __attribute__((ext_vector_type(4)));

// ---------------------------------------------------------------------------
// Prep: pts4[j] = (x, y, z, sq), sq = (x*x + y*y) + z*z in exact reference
// rounding order (contract off, separate mul/add).
// ---------------------------------------------------------------------------
__global__ __launch_bounds__(256) void prep_kernel(const float* __restrict__ pts,
                                                   float4* __restrict__ pts4) {
#pragma clang fp contract(off)
    const int j = blockIdx.x * 256 + threadIdx.x;
    const float x = pts[j * 3 + 0];
    const float y = pts[j * 3 + 1];
    const float z = pts[j * 3 + 2];
    const float sq = (x * x + y * y) + z * z;
    pts4[j] = make_float4(x, y, z, sq);
}

// ---------------------------------------------------------------------------
// Fused exact-kNN + gather. One block (256 threads) per point i.
// Selection phases are byte-identical to the round-6 passing kernel
// (bit-identical thresholds / survivors / ranks). Gather is restructured:
// READ-ONCE / STORE-MANY — out1 (8) and out2 (16) rows are prefixes of
// out3's 32 rows, so each neighbor row is read once and stored 1-3 times.
// 33 reads + 57 stores per point instead of 57 reads + 57 stores.
// Wave wv owns k in {wv, wv+4, ..., wv+28}; all 8 row-reads issued up-front
// (8 outstanding vmem loads), then NT stores. All branches wave-uniform.
// ---------------------------------------------------------------------------
__global__ __launch_bounds__(256) void knn_fused_kernel(const float4* __restrict__ pts4,
                                                        const float* __restrict__ feats,
                                                        float* __restrict__ out) {
#pragma clang fp contract(off)
    const int i = blockIdx.x;
    const int tid = threadIdx.x;
    const int lane = tid & 63;
    const int wv = tid >> 6;

    __shared__ unsigned red[4];
    __shared__ int sh_cnt;
    __shared__ unsigned long long S[SCAP];
    __shared__ unsigned jlist[32];

    const float4 pi = pts4[i];

    unsigned d[32];                       // clamped-d2 bits per owned j
    unsigned m1 = 0xFFFFFFFFu, m2 = 0xFFFFFFFFu;
#pragma unroll
    for (int t = 0; t < 32; ++t) {
        const int j = tid + t * 256;
        const float4 pj = pts4[j];
        const float dot = __builtin_fmaf(pi.z, pj.z, __builtin_fmaf(pi.y, pj.y, pi.x * pj.x));
        const float d2 = (pi.w + pj.w) - (2.0f * dot);
        const unsigned db = __float_as_uint(fmaxf(d2, 0.0f));
        d[t] = db;
        const unsigned mx = db > m1 ? db : m1;   // max(db, m1)
        m1 = db < m1 ? db : m1;                  // min
        m2 = mx < m2 ? mx : m2;                  // 2nd smallest
    }
    if (tid == 0) sh_cnt = 0;

    // --- per-wave ballot binary search: exact 33rd smallest of {m1,m2} ---
    unsigned blo = 0u, bhi = 0x7F800000u;        // finite non-neg float bits
    while (blo < bhi) {
        const unsigned mid = (blo + bhi) >> 1;
        const int cnt = __popcll(__ballot(m1 <= mid)) + __popcll(__ballot(m2 <= mid));
        if (cnt >= KSEL) bhi = mid; else blo = mid + 1u;
    }
    if (lane == 0) red[wv] = bhi;
    __syncthreads();
    unsigned T = red[0];
    T = red[1] < T ? red[1] : T;
    T = red[2] < T ? red[2] : T;
    T = red[3] < T ? red[3] : T;

    // --- widen to sqrt-closure (conservative, provably inclusive) ---
    const float s = sqrtf(__uint_as_float(T));               // CR sqrt
    const float snx = __uint_as_float(__float_as_uint(s) + 1u);
    const unsigned T2 = __float_as_uint(__fmul_rn(snx, snx)) + 2u;

    // --- compact survivors into LDS (CR sqrt only here) ---
    int n = 0;
#pragma unroll
    for (int t = 0; t < 32; ++t) n += (d[t] <= T2) ? 1 : 0;

    int incl = n;
#pragma unroll
    for (int sh = 1; sh < 64; sh <<= 1) {
        const int o = __shfl_up(incl, sh, 64);
        if (lane >= sh) incl += o;
    }
    int base = 0;
    if (lane == 63) base = atomicAdd(&sh_cnt, incl);
    base = __shfl(base, 63, 64);
    int ptr = base + incl - n;
#pragma unroll
    for (int t = 0; t < 32; ++t) {
        if (d[t] <= T2) {
            const unsigned db = __float_as_uint(sqrtf(__uint_as_float(d[t])));
            if (ptr < SCAP)
                S[ptr] = (((unsigned long long)db) << 32) | (unsigned)(tid + t * 256);
            ++ptr;
        }
    }
    __syncthreads();

    // --- exact global rank among survivors (keys unique via j) ---
    const int c = sh_cnt < SCAP ? sh_cnt : SCAP;
    for (int q = tid; q < c; q += 256) {
        const unsigned long long key = S[q];
        int rank = 0;
        for (int u = 0; u < c; ++u) rank += (S[u] < key) ? 1 : 0;
        if (rank >= 1 && rank < KSEL) jlist[rank - 1] = (unsigned)key;
    }
    __syncthreads();

    // --- gather: read-once / store-many ---
    const unsigned long long O1 = (unsigned long long)NPTS * 256ull;
    const unsigned long long O2 = O1 + (unsigned long long)NPTS * 2048ull;
    const unsigned long long O3 = O2 + (unsigned long long)NPTS * 4096ull;
    const unsigned long long ii = (unsigned long long)i;

    // issue all row-reads first (8 neighbor rows per wave, + self on wave 0)
    vf4 vself;
    if (wv == 0) {
        const vf4* sp = (const vf4*)(feats + ii * 256ull);
        vself = sp[lane];
    }
    vf4 vk[8];
    unsigned kk[8];
#pragma unroll
    for (int m = 0; m < 8; ++m) {
        const int k = wv + 4 * m;
        const unsigned src = jlist[k];
        kk[m] = (unsigned)k;
        const vf4* sp = (const vf4*)(feats + (unsigned long long)src * 256ull);
        vk[m] = sp[lane];
    }

    // stores: out3 always; mirror to out2 (k<16) and out1 (k<8)
    if (wv == 0) {
        __builtin_nontemporal_store(vself, &((vf4*)(out + ii * 256ull))[lane]);
    }
#pragma unroll
    for (int m = 0; m < 8; ++m) {
        const unsigned k = kk[m];
        const vf4 v = vk[m];
        __builtin_nontemporal_store(v,
            &((vf4*)(out + O3 + ii * 8192ull + (unsigned long long)k * 256ull))[lane]);
        if (k < 16u)
            __builtin_nontemporal_store(v,
                &((vf4*)(out + O2 + ii * 4096ull + (unsigned long long)k * 256ull))[lane]);
        if (k < 8u)
            __builtin_nontemporal_store(v,
                &((vf4*)(out + O1 + ii * 2048ull + (unsigned long long)k * 256ull))[lane]);
    }
}

extern "C" void kernel_launch(void* const* d_in, const int* in_sizes, int n_in,
                              void* d_out, int out_size, void* d_ws, size_t ws_size,
                              hipStream_t stream) {
    const float* feats = (const float*)d_in[0];   // (8192, 256) f32
    const float* pts = (const float*)d_in[1];     // (8192, 3)   f32
    // d_in[2] = f_masks (all ones; unused by the reference computation)

    float4* pts4 = (float4*)d_ws;                 // 128 KB scratch

    prep_kernel<<<NPTS / 256, 256, 0, stream>>>(pts, pts4);
    knn_fused_kernel<<<NPTS, 256, 0, stream>>>(pts4, feats, (float*)d_out);
}